// Round 7
// baseline (69.347 us; speedup 1.0000x reference)
//
#include <hip/hip_runtime.h>
#include <math.h>

// Problem constants (fixed by the reference)
constexpr int B_ROWS = 16384;
constexpr int D_COLS = 2048;     // 512 float4 per row
constexpr float EPS_F = 1e-8f;

// pass1 tiling: block = (row-chunk rb of 64 rows) x (col-slice cs of 64 float4)
constexpr int NRB = 256;         // row chunks (64 rows each)
constexpr int NCS = 8;           // col slices (64 float4 each)
constexpr int ROWS_PER_RB = 64;
constexpr int ROWS_PER_H = 16;   // 4 row-subsets per column-thread
constexpr int NB2 = 256;         // pass2 blocks (1 per CU)

// ws float layout (no memset — a graph-captured fill costs ~75us flat):
//  [0 .. 1024)             per-rb counts, float4 {c0,c1,c2,c3} x 256
//  [5120 .. 5130)          10 global dot accumulators (atomicAdd targets)
//  [8000] (as int)         ticket counter
//  [16384 .. +256*8192)    partials: record rb (8192 floats = 4 groups x 2048)
// pass1 block 0 zeroes accumulators+ticket each launch; all other ws values
// are replay-invariant, so cross-replay cache staleness is harmless.
constexpr int ACC_IDX = 5120;
constexpr int CNT_IDX = 8000;
constexpr int WS_PART = 16384;   // byte offset 65536, 16B aligned

// ---------------------------------------------------------------------------
// pass1: 2048 blocks x 256 threads, 8 blocks/CU (32 waves/CU). Unchanged from
// the proven R5 kernel except the accumulator/ticket zeroing in block 0.
// ---------------------------------------------------------------------------
__global__ __launch_bounds__(256, 8) void pass1_partial_sums(
    const float* __restrict__ feat, const int* __restrict__ lab,
    const int* __restrict__ ses, float* __restrict__ ws) {
  const int t = threadIdx.x;
  const int rb = blockIdx.x >> 3;
  const int cs = blockIdx.x & 7;
  const int c = t & 63;
  const int h = t >> 6;
  const int row0 = rb * ROWS_PER_RB;

  if (blockIdx.x == 0 && t < 16) {
    if (t < 10) ws[ACC_IDX + t] = 0.f;
    if (t == 15) ((int*)ws)[CNT_IDX] = 0;
  }

  __shared__ float4 w[ROWS_PER_RB];
  __shared__ float4 red[16 * 64];   // [(g*4+h)*64 + c], 16 KB

  if (t < ROWS_PER_RB) {
    const int r = row0 + t;
    const int g = lab[r] * 2 + ses[r];
    w[t] = make_float4(g == 0 ? 1.f : 0.f, g == 1 ? 1.f : 0.f,
                       g == 2 ? 1.f : 0.f, g == 3 ? 1.f : 0.f);
  }
  __syncthreads();

  float4 a0 = {0.f, 0.f, 0.f, 0.f};
  float4 a1 = a0, a2 = a0, a3 = a0;

  const float4* fb = (const float4*)feat
      + (size_t)(row0 + h * ROWS_PER_H) * 512 + cs * 64 + c;
  #pragma unroll 4
  for (int r = 0; r < ROWS_PER_H; ++r) {
    const float4 v = fb[(size_t)r * 512];
    const float4 wr = w[h * ROWS_PER_H + r];
    a0.x += v.x * wr.x; a0.y += v.y * wr.x; a0.z += v.z * wr.x; a0.w += v.w * wr.x;
    a1.x += v.x * wr.y; a1.y += v.y * wr.y; a1.z += v.z * wr.y; a1.w += v.w * wr.y;
    a2.x += v.x * wr.z; a2.y += v.y * wr.z; a2.z += v.z * wr.z; a2.w += v.w * wr.z;
    a3.x += v.x * wr.w; a3.y += v.y * wr.w; a3.z += v.z * wr.w; a3.w += v.w * wr.w;
  }

  red[(0 * 4 + h) * 64 + c] = a0;
  red[(1 * 4 + h) * 64 + c] = a1;
  red[(2 * 4 + h) * 64 + c] = a2;
  red[(3 * 4 + h) * 64 + c] = a3;
  __syncthreads();

  {
    const int g = t >> 6;
    float4 acc = red[(g * 4 + 0) * 64 + c];
    #pragma unroll
    for (int hh = 1; hh < 4; ++hh) {
      const float4 v = red[(g * 4 + hh) * 64 + c];
      acc.x += v.x; acc.y += v.y; acc.z += v.z; acc.w += v.w;
    }
    float4* part = (float4*)(ws + WS_PART);
    part[(size_t)rb * 2048 + g * 512 + cs * 64 + c] = acc;
  }

  if (cs == 0 && t == 0) {
    float4 cnt = {0.f, 0.f, 0.f, 0.f};
    #pragma unroll
    for (int r = 0; r < ROWS_PER_RB; ++r) {
      const float4 wr = w[r];
      cnt.x += wr.x; cnt.y += wr.y; cnt.z += wr.z; cnt.w += wr.w;
    }
    ((float4*)ws)[rb] = cnt;
  }
}

// ---------------------------------------------------------------------------
// pass2 + finalize: 256 blocks x 256 threads (1 block/CU).
// Block b owns float4 columns {2b, 2b+1} of all 4 groups. Each block
// LDS-reduces its columns, then t==0 atomicAdds its 10 dot-partials into
// global accumulators (device-scope; returned values consumed to force
// completion via vmcnt — no __threadfence/L2 flush), takes a ticket; the
// last block reads the finished sums (atomic reads) + counts and writes out.
// ---------------------------------------------------------------------------
__global__ __launch_bounds__(256) void pass2_finalize(
    float* __restrict__ ws, float* __restrict__ out) {
  const int t = threadIdx.x;
  const int b = blockIdx.x;
  const int pair = t & 7;
  const int chunk = t >> 3;            // 0..31
  const int g = pair >> 1;
  const int cl = pair & 1;
  const int j4 = g * 512 + b * 2 + cl;

  float4 s = {0.f, 0.f, 0.f, 0.f};
  const float4* part = (const float4*)(ws + WS_PART);
  #pragma unroll
  for (int p = chunk; p < NRB; p += 32) {
    const float4 v = part[(size_t)p * 2048 + j4];
    s.x += v.x; s.y += v.y; s.z += v.z; s.w += v.w;
  }

  __shared__ float4 lds[256];
  lds[t] = s;                          // [chunk*8 + pair]
  __syncthreads();

  __shared__ float4 sg[4][2];          // [g][cl] = S_g for this float4 column
  if (t < 8) {
    float4 acc = lds[t];
    #pragma unroll
    for (int ch = 1; ch < 32; ++ch) {
      const float4 v = lds[ch * 8 + t];
      acc.x += v.x; acc.y += v.y; acc.z += v.z; acc.w += v.w;
    }
    sg[t >> 1][t & 1] = acc;
  }
  __syncthreads();

  __shared__ int lastFlag;
  if (t == 0) {
    float d[10];
    #pragma unroll
    for (int k = 0; k < 10; ++k) d[k] = 0.f;
    #pragma unroll
    for (int cl2 = 0; cl2 < 2; ++cl2) {
      const float4 s0 = sg[0][cl2], s1 = sg[1][cl2];
      const float4 s2 = sg[2][cl2], s3 = sg[3][cl2];
      d[0] += s0.x*s0.x + s0.y*s0.y + s0.z*s0.z + s0.w*s0.w;   // n0
      d[1] += s1.x*s1.x + s1.y*s1.y + s1.z*s1.z + s1.w*s1.w;   // n1
      d[2] += s2.x*s2.x + s2.y*s2.y + s2.z*s2.z + s2.w*s2.w;   // n2
      d[3] += s3.x*s3.x + s3.y*s3.y + s3.z*s3.z + s3.w*s3.w;   // n3
      d[4] += s0.x*s1.x + s0.y*s1.y + s0.z*s1.z + s0.w*s1.w;   // d01
      d[5] += s2.x*s3.x + s2.y*s3.y + s2.z*s3.z + s2.w*s3.w;   // d23
      d[6] += s0.x*s2.x + s0.y*s2.y + s0.z*s2.z + s0.w*s2.w;   // d02
      d[7] += s0.x*s3.x + s0.y*s3.y + s0.z*s3.z + s0.w*s3.w;   // d03
      d[8] += s1.x*s2.x + s1.y*s2.y + s1.z*s2.z + s1.w*s2.w;   // d12
      d[9] += s1.x*s3.x + s1.y*s3.y + s1.z*s3.z + s1.w*s3.w;   // d13
    }
    float o0 = atomicAdd(ws + ACC_IDX + 0, d[0]);
    float o1 = atomicAdd(ws + ACC_IDX + 1, d[1]);
    float o2 = atomicAdd(ws + ACC_IDX + 2, d[2]);
    float o3 = atomicAdd(ws + ACC_IDX + 3, d[3]);
    float o4 = atomicAdd(ws + ACC_IDX + 4, d[4]);
    float o5 = atomicAdd(ws + ACC_IDX + 5, d[5]);
    float o6 = atomicAdd(ws + ACC_IDX + 6, d[6]);
    float o7 = atomicAdd(ws + ACC_IDX + 7, d[7]);
    float o8 = atomicAdd(ws + ACC_IDX + 8, d[8]);
    float o9 = atomicAdd(ws + ACC_IDX + 9, d[9]);
    // consume returns: forces s_waitcnt on all 10 atomics before the ticket
    asm volatile("" :: "v"(o0), "v"(o1), "v"(o2), "v"(o3), "v"(o4),
                       "v"(o5), "v"(o6), "v"(o7), "v"(o8), "v"(o9));
    const int old = atomicAdd((int*)ws + CNT_IDX, 1);   // device-scope ticket
    lastFlag = (old == NB2 - 1);
  }
  __syncthreads();
  if (!lastFlag) return;

  // ---- finalize (exactly one block; all contributors' atomics completed) ----
  float k0, k1, k2, k3;
  {
    const float4 cta = ((const float4*)ws)[t];          // 256 count records
    k0 = cta.x; k1 = cta.y; k2 = cta.z; k3 = cta.w;
  }
  #pragma unroll
  for (int m = 32; m >= 1; m >>= 1) {
    k0 += __shfl_xor(k0, m, 64);  k1 += __shfl_xor(k1, m, 64);
    k2 += __shfl_xor(k2, m, 64);  k3 += __shfl_xor(k3, m, 64);
  }
  __shared__ float red2[4][4];
  const int wv = t >> 6, ln = t & 63;
  if (ln == 0) {
    red2[wv][0] = k0; red2[wv][1] = k1; red2[wv][2] = k2; red2[wv][3] = k3;
  }
  __syncthreads();

  if (t == 0) {
    const float cn0 = red2[0][0] + red2[1][0] + red2[2][0] + red2[3][0];
    const float cn1 = red2[0][1] + red2[1][1] + red2[2][1] + red2[3][1];
    const float cn2 = red2[0][2] + red2[1][2] + red2[2][2] + red2[3][2];
    const float cn3 = red2[0][3] + red2[1][3] + red2[2][3] + red2[3][3];

    float v[10];
    #pragma unroll
    for (int k = 0; k < 10; ++k)
      v[k] = atomicAdd(ws + ACC_IDX + k, 0.0f);         // device-scope read

    const float NS0 = sqrtf(v[0]), NS1 = sqrtf(v[1]);
    const float NS2 = sqrtf(v[2]), NS3 = sqrtf(v[3]);
    const float N0 = NS0 / cn0, N1 = NS1 / cn1;
    const float N2 = NS2 / cn2, N3 = NS3 / cn3;

    const float c01 = (v[4] / (cn0 * cn1)) / fmaxf(N0 * N1, EPS_F);
    const float c23 = (v[5] / (cn2 * cn3)) / fmaxf(N2 * N3, EPS_F);
    const float c02 = (v[6] / (cn0 * cn2)) / fmaxf(N0 * N2, EPS_F);
    const float c03 = (v[7] / (cn0 * cn3)) / fmaxf(N0 * N3, EPS_F);
    const float c12 = (v[8] / (cn1 * cn2)) / fmaxf(N1 * N2, EPS_F);
    const float c13 = (v[9] / (cn1 * cn3)) / fmaxf(N1 * N3, EPS_F);

    const float center_loss = 1.0f - (NS0 + NS1 + NS2 + NS3) * (1.0f / (float)B_ROWS);
    const float align_loss = ((1.0f - c01) + (1.0f - c23)) * 0.5f;
    const float margin_loss = (c02 + c03 + c12 + c13) * 0.25f;

    out[0] = center_loss + 0.1f * align_loss + 0.05f * margin_loss;
    out[1] = center_loss;
    out[2] = align_loss;
    out[3] = margin_loss;
  }
}

extern "C" void kernel_launch(void* const* d_in, const int* in_sizes, int n_in,
                              void* d_out, int out_size, void* d_ws, size_t ws_size,
                              hipStream_t stream) {
  const float* feat = (const float*)d_in[0];
  const int* lab = (const int*)d_in[1];
  const int* ses = (const int*)d_in[2];
  float* ws = (float*)d_ws;
  float* out = (float*)d_out;

  hipLaunchKernelGGL(pass1_partial_sums, dim3(NRB * NCS), dim3(256), 0, stream,
                     feat, lab, ses, ws);
  hipLaunchKernelGGL(pass2_finalize, dim3(NB2), dim3(256), 0, stream, ws, out);
}

// Round 8
// 32.215 us; speedup vs baseline: 2.1526x; 2.1526x over previous
//
#include <hip/hip_runtime.h>
#include <math.h>

// Problem constants (fixed by the reference)
constexpr int B_ROWS = 16384;
constexpr int D_COLS = 2048;     // 512 float4 per row
constexpr float EPS_F = 1e-8f;

// pass1 tiling: block = (row-chunk rb of 128 rows) x (col-slice cs of 32 float4)
constexpr int NRB = 128;         // row chunks (128 rows each)
constexpr int NCS = 16;          // col slices (32 float4 each)
constexpr int ROWS_PER_RB = 128;
constexpr int NH = 8;            // row-subsets per block (16 rows each)
constexpr int NB2 = 256;         // pass2 blocks (1 per CU)

// ws float layout (every location plain-stored before read; no memset, no
// fences, no atomics — both regressed badly in R6/R7):
//  [0 .. 512)              per-rb counts, float4 {c0,c1,c2,c3} x 128
//  [2048 .. 10240)         csum: 2048 float4 (4 groups x 512), pass2 stores
//  [16384 .. +128*8192)    partials: record rb = 8192 floats (4 g x 2048)
constexpr int WS_CSUM = 2048;    // float index; float4 index 512
constexpr int WS_PART = 16384;   // byte offset 65536, 16B aligned

// ---------------------------------------------------------------------------
// pass1: 2048 blocks x 256 threads, 8 blocks/CU (32 waves/CU — the R5 win).
// Thread (c = t&31, h = t>>5) accumulates 16 rows of float4 column cs*32+c
// into 4 one-hot-weighted group accumulators; LDS-combines the 8 row-subsets;
// 128 threads store the 4x32 float4 slice of record rb.
// ---------------------------------------------------------------------------
__global__ __launch_bounds__(256, 8) void pass1_partial_sums(
    const float* __restrict__ feat, const int* __restrict__ lab,
    const int* __restrict__ ses, float* __restrict__ ws) {
  const int t = threadIdx.x;
  const int rb = blockIdx.x >> 4;
  const int cs = blockIdx.x & 15;
  const int c = t & 31;
  const int h = t >> 5;
  const int row0 = rb * ROWS_PER_RB;

  __shared__ float4 w[ROWS_PER_RB];
  __shared__ float4 red[4 * NH * 32];   // [(g*8+h)*32 + c], 16 KB

  if (t < ROWS_PER_RB) {
    const int r = row0 + t;
    const int g = lab[r] * 2 + ses[r];
    w[t] = make_float4(g == 0 ? 1.f : 0.f, g == 1 ? 1.f : 0.f,
                       g == 2 ? 1.f : 0.f, g == 3 ? 1.f : 0.f);
  }
  __syncthreads();

  float4 a0 = {0.f, 0.f, 0.f, 0.f};
  float4 a1 = a0, a2 = a0, a3 = a0;

  const float4* fb = (const float4*)feat
      + (size_t)(row0 + h * 16) * 512 + cs * 32 + c;
  #pragma unroll 4
  for (int r = 0; r < 16; ++r) {
    const float4 v = fb[(size_t)r * 512];
    const float4 wr = w[h * 16 + r];
    a0.x += v.x * wr.x; a0.y += v.y * wr.x; a0.z += v.z * wr.x; a0.w += v.w * wr.x;
    a1.x += v.x * wr.y; a1.y += v.y * wr.y; a1.z += v.z * wr.y; a1.w += v.w * wr.y;
    a2.x += v.x * wr.z; a2.y += v.y * wr.z; a2.z += v.z * wr.z; a2.w += v.w * wr.z;
    a3.x += v.x * wr.w; a3.y += v.y * wr.w; a3.z += v.z * wr.w; a3.w += v.w * wr.w;
  }

  red[(0 * NH + h) * 32 + c] = a0;
  red[(1 * NH + h) * 32 + c] = a1;
  red[(2 * NH + h) * 32 + c] = a2;
  red[(3 * NH + h) * 32 + c] = a3;
  __syncthreads();

  if (t < 128) {
    const int g = t >> 5;
    const int cc = t & 31;
    float4 acc = red[(g * NH + 0) * 32 + cc];
    #pragma unroll
    for (int hh = 1; hh < NH; ++hh) {
      const float4 v = red[(g * NH + hh) * 32 + cc];
      acc.x += v.x; acc.y += v.y; acc.z += v.z; acc.w += v.w;
    }
    float4* part = (float4*)(ws + WS_PART);
    part[(size_t)rb * 2048 + g * 512 + cs * 32 + cc] = acc;
  }

  if (cs == 0 && t == 0) {
    float4 cnt = {0.f, 0.f, 0.f, 0.f};
    #pragma unroll
    for (int r = 0; r < ROWS_PER_RB; ++r) {
      const float4 wr = w[r];
      cnt.x += wr.x; cnt.y += wr.y; cnt.z += wr.z; cnt.w += wr.w;
    }
    ((float4*)ws)[rb] = cnt;
  }
}

// ---------------------------------------------------------------------------
// pass2: 256 blocks x 256 threads (1 block/CU). Block b owns 8 CONTIGUOUS
// float4 columns (j4 = b*8 + (t&7)) -> each wave reads 128 B contiguous per
// record (full cache-line use). chunk = t>>3 sums 4 records (stride 32 KB);
// 32-chunk LDS tree -> plain-store csum[j4]. No fences, no atomics.
// ---------------------------------------------------------------------------
__global__ __launch_bounds__(256) void pass2_reduce(float* __restrict__ ws) {
  const int t = threadIdx.x;
  const int b = blockIdx.x;
  const int cl = t & 7;
  const int chunk = t >> 3;            // 0..31
  const int j4 = b * 8 + cl;           // 0..2047

  float4 s = {0.f, 0.f, 0.f, 0.f};
  const float4* part = (const float4*)(ws + WS_PART);
  #pragma unroll
  for (int p = chunk; p < NRB; p += 32) {
    const float4 v = part[(size_t)p * 2048 + j4];
    s.x += v.x; s.y += v.y; s.z += v.z; s.w += v.w;
  }

  __shared__ float4 lds[256];
  lds[t] = s;                          // [chunk*8 + cl]
  __syncthreads();

  if (t < 8) {
    float4 acc = lds[t];
    #pragma unroll
    for (int ch = 1; ch < 32; ++ch) {
      const float4 v = lds[ch * 8 + t];
      acc.x += v.x; acc.y += v.y; acc.z += v.z; acc.w += v.w;
    }
    ((float4*)(ws + WS_CSUM))[b * 8 + t] = acc;
  }
}

// ---------------------------------------------------------------------------
// pass3: 1 block x 256 threads. Coalesced float4 reads of csum (32 KB,
// L2-hit): thread t handles float4 columns t and t+256 of each group,
// accumulates the 10 dot products + 128 count records, wave-reduces,
// finalizes.  center_loss = 1 - (sum_g ||S_g||)/B  (inputs are unit-norm).
// ---------------------------------------------------------------------------
__global__ __launch_bounds__(256) void pass3_finalize(
    const float* __restrict__ ws, float* __restrict__ out) {
  const int t = threadIdx.x;
  const float4* csum = (const float4*)(ws + WS_CSUM);
  float n0 = 0, n1 = 0, n2 = 0, n3 = 0;
  float d01 = 0, d23 = 0, d02 = 0, d03 = 0, d12 = 0, d13 = 0;
  float k0 = 0, k1 = 0, k2 = 0, k3 = 0;

  #pragma unroll
  for (int jj = 0; jj < 2; ++jj) {
    const int j = t + jj * 256;        // 0..511
    const float4 s0 = csum[j];
    const float4 s1 = csum[512 + j];
    const float4 s2 = csum[1024 + j];
    const float4 s3 = csum[1536 + j];
    n0 += s0.x*s0.x + s0.y*s0.y + s0.z*s0.z + s0.w*s0.w;
    n1 += s1.x*s1.x + s1.y*s1.y + s1.z*s1.z + s1.w*s1.w;
    n2 += s2.x*s2.x + s2.y*s2.y + s2.z*s2.z + s2.w*s2.w;
    n3 += s3.x*s3.x + s3.y*s3.y + s3.z*s3.z + s3.w*s3.w;
    d01 += s0.x*s1.x + s0.y*s1.y + s0.z*s1.z + s0.w*s1.w;
    d23 += s2.x*s3.x + s2.y*s3.y + s2.z*s3.z + s2.w*s3.w;
    d02 += s0.x*s2.x + s0.y*s2.y + s0.z*s2.z + s0.w*s2.w;
    d03 += s0.x*s3.x + s0.y*s3.y + s0.z*s3.z + s0.w*s3.w;
    d12 += s1.x*s2.x + s1.y*s2.y + s1.z*s2.z + s1.w*s2.w;
    d13 += s1.x*s3.x + s1.y*s3.y + s1.z*s3.z + s1.w*s3.w;
  }
  if (t < NRB) {
    const float4 cta = ((const float4*)ws)[t];     // 128 count records
    k0 = cta.x; k1 = cta.y; k2 = cta.z; k3 = cta.w;
  }

  #pragma unroll
  for (int m = 32; m >= 1; m >>= 1) {
    n0  += __shfl_xor(n0, m, 64);  n1  += __shfl_xor(n1, m, 64);
    n2  += __shfl_xor(n2, m, 64);  n3  += __shfl_xor(n3, m, 64);
    d01 += __shfl_xor(d01, m, 64); d23 += __shfl_xor(d23, m, 64);
    d02 += __shfl_xor(d02, m, 64); d03 += __shfl_xor(d03, m, 64);
    d12 += __shfl_xor(d12, m, 64); d13 += __shfl_xor(d13, m, 64);
    k0  += __shfl_xor(k0, m, 64);  k1  += __shfl_xor(k1, m, 64);
    k2  += __shfl_xor(k2, m, 64);  k3  += __shfl_xor(k3, m, 64);
  }

  __shared__ float red[4][14];
  const int wv = t >> 6, ln = t & 63;
  if (ln == 0) {
    red[wv][0] = n0;  red[wv][1] = n1;  red[wv][2] = n2;  red[wv][3] = n3;
    red[wv][4] = d01; red[wv][5] = d23; red[wv][6] = d02; red[wv][7] = d03;
    red[wv][8] = d12; red[wv][9] = d13;
    red[wv][10] = k0; red[wv][11] = k1; red[wv][12] = k2; red[wv][13] = k3;
  }
  __syncthreads();

  if (t == 0) {
    float v[14];
    #pragma unroll
    for (int k = 0; k < 14; ++k)
      v[k] = red[0][k] + red[1][k] + red[2][k] + red[3][k];

    const float NS0 = sqrtf(v[0]), NS1 = sqrtf(v[1]);
    const float NS2 = sqrtf(v[2]), NS3 = sqrtf(v[3]);
    const float cn0 = v[10], cn1 = v[11], cn2 = v[12], cn3 = v[13];
    const float N0 = NS0 / cn0, N1 = NS1 / cn1;
    const float N2 = NS2 / cn2, N3 = NS3 / cn3;

    const float c01 = (v[4] / (cn0 * cn1)) / fmaxf(N0 * N1, EPS_F);
    const float c23 = (v[5] / (cn2 * cn3)) / fmaxf(N2 * N3, EPS_F);
    const float c02 = (v[6] / (cn0 * cn2)) / fmaxf(N0 * N2, EPS_F);
    const float c03 = (v[7] / (cn0 * cn3)) / fmaxf(N0 * N3, EPS_F);
    const float c12 = (v[8] / (cn1 * cn2)) / fmaxf(N1 * N2, EPS_F);
    const float c13 = (v[9] / (cn1 * cn3)) / fmaxf(N1 * N3, EPS_F);

    const float center_loss = 1.0f - (NS0 + NS1 + NS2 + NS3) * (1.0f / (float)B_ROWS);
    const float align_loss = ((1.0f - c01) + (1.0f - c23)) * 0.5f;
    const float margin_loss = (c02 + c03 + c12 + c13) * 0.25f;

    out[0] = center_loss + 0.1f * align_loss + 0.05f * margin_loss;
    out[1] = center_loss;
    out[2] = align_loss;
    out[3] = margin_loss;
  }
}

extern "C" void kernel_launch(void* const* d_in, const int* in_sizes, int n_in,
                              void* d_out, int out_size, void* d_ws, size_t ws_size,
                              hipStream_t stream) {
  const float* feat = (const float*)d_in[0];
  const int* lab = (const int*)d_in[1];
  const int* ses = (const int*)d_in[2];
  float* ws = (float*)d_ws;
  float* out = (float*)d_out;

  hipLaunchKernelGGL(pass1_partial_sums, dim3(NRB * NCS), dim3(256), 0, stream,
                     feat, lab, ses, ws);
  hipLaunchKernelGGL(pass2_reduce, dim3(NB2), dim3(256), 0, stream, ws);
  hipLaunchKernelGGL(pass3_finalize, dim3(1), dim3(256), 0, stream, ws, out);
}

// Round 9
// 32.126 us; speedup vs baseline: 2.1586x; 1.0028x over previous
//
#include <hip/hip_runtime.h>
#include <math.h>

// Problem constants (fixed by the reference)
constexpr int B_ROWS = 16384;
constexpr int D_COLS = 2048;     // 512 float4 per row
constexpr float EPS_F = 1e-8f;

// pass1 tiling: block = (row-chunk rb of 256 rows) x (col-slice cs of 16 float4)
constexpr int NRB = 64;          // row chunks (256 rows each)
constexpr int NCS = 32;          // col slices (16 float4 each)
constexpr int ROWS_PER_RB = 256;
constexpr int NH = 16;           // row-subsets per block (16 rows each)
constexpr int NB2 = 256;         // pass2 blocks (1 per CU)

// ws float layout (every location plain-stored before read; no memset, no
// fences, no atomics — R1/R6/R7 showed each of those regresses):
//  [0 .. 256)              per-rb counts, float4 {c0,c1,c2,c3} x 64
//  [2048 .. 10240)         csum: 2048 float4 (4 groups x 512), pass2 stores
//  [16384 .. +64*8192)     partials: record rb = 8192 floats (4 g x 2048)
constexpr int WS_CSUM = 2048;    // float index; float4 index 512
constexpr int WS_PART = 16384;   // byte offset 65536, 16B aligned

// ---------------------------------------------------------------------------
// pass1: 2048 blocks x 256 threads, 8 blocks/CU (32 waves/CU — the R5 win).
// Thread (c = t&15, h = t>>4) accumulates 16 rows of float4 column cs*16+c
// into 4 one-hot-weighted group accumulators; LDS-combines the 16 row-subsets;
// 64 threads store the 4x16 float4 slice of record rb.
// ---------------------------------------------------------------------------
__global__ __launch_bounds__(256, 8) void pass1_partial_sums(
    const float* __restrict__ feat, const int* __restrict__ lab,
    const int* __restrict__ ses, float* __restrict__ ws) {
  const int t = threadIdx.x;
  const int rb = blockIdx.x >> 5;
  const int cs = blockIdx.x & 31;
  const int c = t & 15;
  const int h = t >> 4;
  const int row0 = rb * ROWS_PER_RB;

  __shared__ float4 w[ROWS_PER_RB];        // 4 KB one-hot weights
  __shared__ float4 red[4 * NH * 16];      // [(g*16+h)*16 + c], 16 KB

  {
    const int r = row0 + t;                // 256 threads, 256 rows
    const int g = lab[r] * 2 + ses[r];
    w[t] = make_float4(g == 0 ? 1.f : 0.f, g == 1 ? 1.f : 0.f,
                       g == 2 ? 1.f : 0.f, g == 3 ? 1.f : 0.f);
  }
  __syncthreads();

  float4 a0 = {0.f, 0.f, 0.f, 0.f};
  float4 a1 = a0, a2 = a0, a3 = a0;

  const float4* fb = (const float4*)feat
      + (size_t)(row0 + h * 16) * 512 + cs * 16 + c;
  #pragma unroll 4
  for (int r = 0; r < 16; ++r) {
    const float4 v = fb[(size_t)r * 512];
    const float4 wr = w[h * 16 + r];
    a0.x += v.x * wr.x; a0.y += v.y * wr.x; a0.z += v.z * wr.x; a0.w += v.w * wr.x;
    a1.x += v.x * wr.y; a1.y += v.y * wr.y; a1.z += v.z * wr.y; a1.w += v.w * wr.y;
    a2.x += v.x * wr.z; a2.y += v.y * wr.z; a2.z += v.z * wr.z; a2.w += v.w * wr.z;
    a3.x += v.x * wr.w; a3.y += v.y * wr.w; a3.z += v.z * wr.w; a3.w += v.w * wr.w;
  }

  red[(0 * NH + h) * 16 + c] = a0;
  red[(1 * NH + h) * 16 + c] = a1;
  red[(2 * NH + h) * 16 + c] = a2;
  red[(3 * NH + h) * 16 + c] = a3;
  __syncthreads();

  if (t < 64) {
    const int g = t >> 4;
    const int cc = t & 15;
    float4 acc = red[(g * NH + 0) * 16 + cc];
    #pragma unroll
    for (int hh = 1; hh < NH; ++hh) {
      const float4 v = red[(g * NH + hh) * 16 + cc];
      acc.x += v.x; acc.y += v.y; acc.z += v.z; acc.w += v.w;
    }
    float4* part = (float4*)(ws + WS_PART);
    part[(size_t)rb * 2048 + g * 512 + cs * 16 + cc] = acc;
  }

  if (cs == 0 && t == 0) {
    float4 cnt = {0.f, 0.f, 0.f, 0.f};
    #pragma unroll
    for (int r = 0; r < ROWS_PER_RB; ++r) {
      const float4 wr = w[r];
      cnt.x += wr.x; cnt.y += wr.y; cnt.z += wr.z; cnt.w += wr.w;
    }
    ((float4*)ws)[rb] = cnt;
  }
}

// ---------------------------------------------------------------------------
// pass2: 256 blocks x 256 threads (1 block/CU). Block b owns 8 CONTIGUOUS
// float4 columns (j4 = b*8 + (t&7)) -> each wave reads 128 B contiguous per
// record. chunk = t>>3 sums 2 records (64 records, stride 32 KB); 32-chunk
// LDS tree -> plain-store csum[j4]. No fences, no atomics.
// ---------------------------------------------------------------------------
__global__ __launch_bounds__(256) void pass2_reduce(float* __restrict__ ws) {
  const int t = threadIdx.x;
  const int b = blockIdx.x;
  const int cl = t & 7;
  const int chunk = t >> 3;            // 0..31
  const int j4 = b * 8 + cl;           // 0..2047

  float4 s = {0.f, 0.f, 0.f, 0.f};
  const float4* part = (const float4*)(ws + WS_PART);
  #pragma unroll
  for (int p = chunk; p < NRB; p += 32) {
    const float4 v = part[(size_t)p * 2048 + j4];
    s.x += v.x; s.y += v.y; s.z += v.z; s.w += v.w;
  }

  __shared__ float4 lds[256];
  lds[t] = s;                          // [chunk*8 + cl]
  __syncthreads();

  if (t < 8) {
    float4 acc = lds[t];
    #pragma unroll
    for (int ch = 1; ch < 32; ++ch) {
      const float4 v = lds[ch * 8 + t];
      acc.x += v.x; acc.y += v.y; acc.z += v.z; acc.w += v.w;
    }
    ((float4*)(ws + WS_CSUM))[b * 8 + t] = acc;
  }
}

// ---------------------------------------------------------------------------
// pass3: 1 block x 256 threads. Coalesced float4 reads of csum (32 KB,
// L2-hit); 10 dot products + 64 count records; wave-reduce; finalize.
//   center_loss = 1 - (sum_g ||S_g||)/B   (inputs are unit-norm)
// ---------------------------------------------------------------------------
__global__ __launch_bounds__(256) void pass3_finalize(
    const float* __restrict__ ws, float* __restrict__ out) {
  const int t = threadIdx.x;
  const float4* csum = (const float4*)(ws + WS_CSUM);
  float n0 = 0, n1 = 0, n2 = 0, n3 = 0;
  float d01 = 0, d23 = 0, d02 = 0, d03 = 0, d12 = 0, d13 = 0;
  float k0 = 0, k1 = 0, k2 = 0, k3 = 0;

  #pragma unroll
  for (int jj = 0; jj < 2; ++jj) {
    const int j = t + jj * 256;        // 0..511
    const float4 s0 = csum[j];
    const float4 s1 = csum[512 + j];
    const float4 s2 = csum[1024 + j];
    const float4 s3 = csum[1536 + j];
    n0 += s0.x*s0.x + s0.y*s0.y + s0.z*s0.z + s0.w*s0.w;
    n1 += s1.x*s1.x + s1.y*s1.y + s1.z*s1.z + s1.w*s1.w;
    n2 += s2.x*s2.x + s2.y*s2.y + s2.z*s2.z + s2.w*s2.w;
    n3 += s3.x*s3.x + s3.y*s3.y + s3.z*s3.z + s3.w*s3.w;
    d01 += s0.x*s1.x + s0.y*s1.y + s0.z*s1.z + s0.w*s1.w;
    d23 += s2.x*s3.x + s2.y*s3.y + s2.z*s3.z + s2.w*s3.w;
    d02 += s0.x*s2.x + s0.y*s2.y + s0.z*s2.z + s0.w*s2.w;
    d03 += s0.x*s3.x + s0.y*s3.y + s0.z*s3.z + s0.w*s3.w;
    d12 += s1.x*s2.x + s1.y*s2.y + s1.z*s2.z + s1.w*s2.w;
    d13 += s1.x*s3.x + s1.y*s3.y + s1.z*s3.z + s1.w*s3.w;
  }
  if (t < NRB) {
    const float4 cta = ((const float4*)ws)[t];     // 64 count records
    k0 = cta.x; k1 = cta.y; k2 = cta.z; k3 = cta.w;
  }

  #pragma unroll
  for (int m = 32; m >= 1; m >>= 1) {
    n0  += __shfl_xor(n0, m, 64);  n1  += __shfl_xor(n1, m, 64);
    n2  += __shfl_xor(n2, m, 64);  n3  += __shfl_xor(n3, m, 64);
    d01 += __shfl_xor(d01, m, 64); d23 += __shfl_xor(d23, m, 64);
    d02 += __shfl_xor(d02, m, 64); d03 += __shfl_xor(d03, m, 64);
    d12 += __shfl_xor(d12, m, 64); d13 += __shfl_xor(d13, m, 64);
    k0  += __shfl_xor(k0, m, 64);  k1  += __shfl_xor(k1, m, 64);
    k2  += __shfl_xor(k2, m, 64);  k3  += __shfl_xor(k3, m, 64);
  }

  __shared__ float red[4][14];
  const int wv = t >> 6, ln = t & 63;
  if (ln == 0) {
    red[wv][0] = n0;  red[wv][1] = n1;  red[wv][2] = n2;  red[wv][3] = n3;
    red[wv][4] = d01; red[wv][5] = d23; red[wv][6] = d02; red[wv][7] = d03;
    red[wv][8] = d12; red[wv][9] = d13;
    red[wv][10] = k0; red[wv][11] = k1; red[wv][12] = k2; red[wv][13] = k3;
  }
  __syncthreads();

  if (t == 0) {
    float v[14];
    #pragma unroll
    for (int k = 0; k < 14; ++k)
      v[k] = red[0][k] + red[1][k] + red[2][k] + red[3][k];

    const float NS0 = sqrtf(v[0]), NS1 = sqrtf(v[1]);
    const float NS2 = sqrtf(v[2]), NS3 = sqrtf(v[3]);
    const float cn0 = v[10], cn1 = v[11], cn2 = v[12], cn3 = v[13];
    const float N0 = NS0 / cn0, N1 = NS1 / cn1;
    const float N2 = NS2 / cn2, N3 = NS3 / cn3;

    const float c01 = (v[4] / (cn0 * cn1)) / fmaxf(N0 * N1, EPS_F);
    const float c23 = (v[5] / (cn2 * cn3)) / fmaxf(N2 * N3, EPS_F);
    const float c02 = (v[6] / (cn0 * cn2)) / fmaxf(N0 * N2, EPS_F);
    const float c03 = (v[7] / (cn0 * cn3)) / fmaxf(N0 * N3, EPS_F);
    const float c12 = (v[8] / (cn1 * cn2)) / fmaxf(N1 * N2, EPS_F);
    const float c13 = (v[9] / (cn1 * cn3)) / fmaxf(N1 * N3, EPS_F);

    const float center_loss = 1.0f - (NS0 + NS1 + NS2 + NS3) * (1.0f / (float)B_ROWS);
    const float align_loss = ((1.0f - c01) + (1.0f - c23)) * 0.5f;
    const float margin_loss = (c02 + c03 + c12 + c13) * 0.25f;

    out[0] = center_loss + 0.1f * align_loss + 0.05f * margin_loss;
    out[1] = center_loss;
    out[2] = align_loss;
    out[3] = margin_loss;
  }
}

extern "C" void kernel_launch(void* const* d_in, const int* in_sizes, int n_in,
                              void* d_out, int out_size, void* d_ws, size_t ws_size,
                              hipStream_t stream) {
  const float* feat = (const float*)d_in[0];
  const int* lab = (const int*)d_in[1];
  const int* ses = (const int*)d_in[2];
  float* ws = (float*)d_ws;
  float* out = (float*)d_out;

  hipLaunchKernelGGL(pass1_partial_sums, dim3(NRB * NCS), dim3(256), 0, stream,
                     feat, lab, ses, ws);
  hipLaunchKernelGGL(pass2_reduce, dim3(NB2), dim3(256), 0, stream, ws);
  hipLaunchKernelGGL(pass3_finalize, dim3(1), dim3(256), 0, stream, ws, out);
}